// Round 3
// baseline (250.559 us; speedup 1.0000x reference)
//
#include <hip/hip_runtime.h>

// Walsh-Hadamard transform, N=4096 per row, fp32, scale 1/sqrt(4096)=1/64.
// R3: H_4096 = H_64 (x) H_64, ONE WAVE PER ROW, zero inter-wave barriers.
//
// R2 counters showed VALUBusy=14%, HBM=31%, Occ=57% -- all pipes idle =>
// latency-bound on the barrier-phase-locked structure (3-4 syncthreads/row).
// New structure: 64-thread blocks (1 wave). Lane l holds 64 elements in VGPRs.
//   pass 1: v[j] = x[j*64+l]  (64 coalesced dword loads), WHT64 in-lane = hi digit
//   transpose: single-wave LDS roundtrip, 64x65 padded (2-way conflicts only,
//              const-offset ds_write_b32 x64 / ds_read_b128 x16)
//   pass 2: WHT64 in-lane = lo digit, scale, store 16x dwordx4 (lane-contig 256B)
// LDS/block = 64*65*4 = 16640 B -> 9 blocks/CU; waves fully autonomous, each
// with 16KB of loads in flight -> continuous HBM demand (fills saturate HBM at
// 9.7% occupancy; latency-BW product needs only ~9KB outstanding per CU).

constexpr int N = 4096;
constexpr int PAD = 65;   // 64+1: (65*l + k) % 32 = (l+k) % 32 -> 2-way only (free)

__device__ __forceinline__ void wht64(float v[64]) {
#pragma unroll
    for (int m = 1; m < 64; m <<= 1) {
#pragma unroll
        for (int g = 0; g < 64; g += 2 * m) {
#pragma unroll
            for (int k = 0; k < m; ++k) {
                float a = v[g + k];
                float b = v[g + k + m];
                v[g + k]     = a + b;
                v[g + k + m] = a - b;
            }
        }
    }
}

__global__ __launch_bounds__(64, 2) void fwht4096_kernel(const float* __restrict__ in,
                                                         float* __restrict__ out) {
    __shared__ float lds[64 * PAD];   // 16640 B

    const int l = threadIdx.x;        // lane, 0..63
    const size_t row = blockIdx.x;
    const float* __restrict__ src = in + row * (size_t)N;
    float* __restrict__ dst = out + row * (size_t)N;

    float v[64];

    // ---- load: v[j] = x[j*64 + l]; instr j is 256B fully coalesced ----
#pragma unroll
    for (int j = 0; j < 64; ++j) v[j] = src[j * 64 + l];

    wht64(v);   // hi digit: y1[h*64+l] = sum_j +-x[j*64+l]; lane l holds y1[h][l]

    // ---- single-wave transpose: lds[j][l] at phys j*65+l ----
    // write instr j: banks (j+l)%32 -> 2-way. const offset j*260.
    {
        const int wbase = l;
#pragma unroll
        for (int j = 0; j < 64; ++j) lds[wbase + j * PAD] = v[j];
    }
    __syncthreads();   // single-wave block: just a lgkmcnt drain + trivial barrier
    // read: lane l takes row l: v[k] = lds[l*65 + k], contiguous -> b128-able,
    // banks (l+k)%32 -> 2-way.
    {
        const int rbase = l * PAD;
#pragma unroll
        for (int k = 0; k < 64; ++k) v[k] = lds[rbase + k];
    }

    wht64(v);   // lo digit: lane l now holds out[l*64 + k], k=0..63 contiguous

    // ---- store: 16x dwordx4, lane l covers bytes [l*256, l*256+256) ----
    const float scale = 0.015625f;  // 1/64 = 1/sqrt(4096)
    float4* __restrict__ d4 = (float4*)(dst + l * 64);
#pragma unroll
    for (int r = 0; r < 16; ++r) {
        d4[r] = make_float4(v[4 * r + 0] * scale, v[4 * r + 1] * scale,
                            v[4 * r + 2] * scale, v[4 * r + 3] * scale);
    }
}

extern "C" void kernel_launch(void* const* d_in, const int* in_sizes, int n_in,
                              void* d_out, int out_size, void* d_ws, size_t ws_size,
                              hipStream_t stream) {
    const float* x = (const float*)d_in[0];
    float* y = (float*)d_out;
    const int rows = in_sizes[0] / N;   // 4*2048 = 8192
    fwht4096_kernel<<<rows, 64, 0, stream>>>(x, y);
}

// Round 4
// 232.816 us; speedup vs baseline: 1.0762x; 1.0762x over previous
//
#include <hip/hip_runtime.h>

// Walsh-Hadamard transform, N=4096, fp32, scale 1/64. H4096 = H16^(x)3.
//
// R4: LDS double-buffered row pipeline with global_load_lds prefetch,
// raw s_barrier + counted vmcnt (never vmcnt(0) in steady state).
//   - R2/R3 post-mortem: register prefetch is destroyed by the register
//     allocator (VGPR 28 / 68); __syncthreads() lowers to s_waitcnt vmcnt(0)
//     + s_barrier, draining any prefetch at every barrier (m97 mechanism).
//   - Fix: prefetch row r+GRID into the spare 16KB LDS buffer via
//     __builtin_amdgcn_global_load_lds (width 16, zero VGPR cost); at the
//     row boundary wait vmcnt(4) (= exactly the 4 stage loads of the buffer
//     we are about to read; the 4 output stores keep draining behind).
//   - Persistent grid: 768 blocks = 3/CU (LDS 50176 B/block), each ~11 rows.
// Pass order c,b,a (digit c = bits 8-11 first from the linear staged buffer):
//   pass c: v[j] = buf[j*256 + t]          (bank = t%32 -> 2-way, free)
//   T1: scr[(j*16+(t&15))*17 + (t>>4)]     (~2-3-way), read scr[t*17+p] (free)
//   pass b, T2: scr[((t>>4)*16+p)*17+(t&15)] (2-way, free), read scr[t*17+p]
//   pass a, store dst[t*16+p]: 4x dwordx4, thread-contiguous 64B.

constexpr int N = 4096;
constexpr int SCR_STRIDE = 17;     // 16+1 pad
constexpr int GRID = 768;          // 3 blocks/CU x 256 CUs, persistent

__device__ __forceinline__ void wht16(float v[16]) {
#pragma unroll
    for (int m = 1; m < 16; m <<= 1) {
#pragma unroll
        for (int g = 0; g < 16; g += 2 * m) {
#pragma unroll
            for (int k = 0; k < m; ++k) {
                float a = v[g + k];
                float b = v[g + k + m];
                v[g + k]     = a + b;
                v[g + k + m] = a - b;
            }
        }
    }
}

// Stage one 16KB row into LDS, linear layout. Wave w covers floats
// [w*1024, (w+1)*1024); call k stages 1KB: lane l -> 16B at granule
// w*256 + k*64 + l. LDS dest is wave-uniform base (HW adds lane*16).
__device__ __forceinline__ void stage_row(const float* __restrict__ src,
                                          float* lbuf, int t) {
    const int w = t >> 6;
    const int l = t & 63;
    const float* gp = src + w * 1024 + l * 4;
    float* lp = lbuf + w * 1024;    // wave-uniform
#pragma unroll
    for (int k = 0; k < 4; ++k) {
        __builtin_amdgcn_global_load_lds(
            (const __attribute__((address_space(1))) unsigned int*)(gp + k * 256),
            (__attribute__((address_space(3))) unsigned int*)(lp + k * 256),
            16, 0, 0);
    }
}

__global__ __launch_bounds__(256, 3) void fwht4096_kernel(const float* __restrict__ in,
                                                          float* __restrict__ out,
                                                          int rows) {
    __shared__ float buf[2][4096];            // 32768 B
    __shared__ float scr[256 * SCR_STRIDE];   // 17408 B

    const int t = threadIdx.x;
    int r = blockIdx.x;
    if (r >= rows) return;
    int cur = 0;

    // prologue: stage first row, full drain (only this wait is vmcnt(0))
    stage_row(in + (size_t)r * N, buf[0], t);
    asm volatile("s_waitcnt vmcnt(0)" ::: "memory");
    __builtin_amdgcn_s_barrier();

    while (r < rows) {
        const int nxt = r + GRID;
        // issue next row's stage FIRST: in flight across the whole compute
        if (nxt < rows) stage_row(in + (size_t)nxt * N, buf[cur ^ 1], t);
        asm volatile("" ::: "memory");   // pin stage issue before the LDS reads

        float v[16];
        const float* bc = buf[cur];

        // ---- pass 1: digit c ----
#pragma unroll
        for (int j = 0; j < 16; ++j) v[j] = bc[j * 256 + t];
        wht16(v);

        // ---- T1 write: i1 = c'*256 + a*16 + b, phys = (i1>>4)*17 + (i1&15) ----
        {
            const int base = (t & 15) * SCR_STRIDE + (t >> 4);
#pragma unroll
            for (int j = 0; j < 16; ++j) scr[base + j * 16 * SCR_STRIDE] = v[j];
        }
        asm volatile("s_waitcnt lgkmcnt(0)" ::: "memory");
        __builtin_amdgcn_s_barrier();
        // ---- T1 read: contiguous, thread u holds (c'=u>>4, a=u&15), p = b ----
        {
            const int base = t * SCR_STRIDE;
#pragma unroll
            for (int p = 0; p < 16; ++p) v[p] = scr[base + p];
        }
        wht16(v);   // digit b done
        asm volatile("s_waitcnt lgkmcnt(0)" ::: "memory");
        __builtin_amdgcn_s_barrier();    // WAR: all T1 reads done before T2 writes

        // ---- T2 write: i2 = c'*256 + b'*16 + a, phys = ((t>>4)*16+p)*17 + (t&15) ----
        {
            const int base = (t >> 4) * 16 * SCR_STRIDE + (t & 15);
#pragma unroll
            for (int p = 0; p < 16; ++p) scr[base + p * SCR_STRIDE] = v[p];
        }
        asm volatile("s_waitcnt lgkmcnt(0)" ::: "memory");
        __builtin_amdgcn_s_barrier();
        // ---- T2 read: contiguous, thread holds (c'=t>>4, b'=t&15), p = a ----
        {
            const int base = t * SCR_STRIDE;
#pragma unroll
            for (int p = 0; p < 16; ++p) v[p] = scr[base + p];
        }
        wht16(v);   // digit a done

        // ---- store: e = t*16 + p -> 4x dwordx4, 64B contiguous per thread ----
        {
            const float scale = 0.015625f;  // 1/64
            float4* d4 = (float4*)(out + (size_t)r * N + t * 16);
#pragma unroll
            for (int q = 0; q < 4; ++q)
                d4[q] = make_float4(v[4 * q + 0] * scale, v[4 * q + 1] * scale,
                                    v[4 * q + 2] * scale, v[4 * q + 3] * scale);
        }

        r = nxt;
        cur ^= 1;
        if (r < rows) {
            // wait for the 4 stage loads of the buffer we'll read next
            // (FIFO: [stage(4), stores(4)] -> vmcnt(4) retires exactly the stage;
            // stores keep draining). Raw barrier: no compiler vmcnt(0) drain.
            asm volatile("s_waitcnt vmcnt(4) lgkmcnt(0)" ::: "memory");
            __builtin_amdgcn_s_barrier();
        }
    }
}

extern "C" void kernel_launch(void* const* d_in, const int* in_sizes, int n_in,
                              void* d_out, int out_size, void* d_ws, size_t ws_size,
                              hipStream_t stream) {
    const float* x = (const float*)d_in[0];
    float* y = (float*)d_out;
    const int rows = in_sizes[0] / N;   // 8192
    fwht4096_kernel<<<GRID, 256, 0, stream>>>(x, y, rows);
}

// Round 5
// 229.743 us; speedup vs baseline: 1.0906x; 1.0134x over previous
//
#include <hip/hip_runtime.h>

// Walsh-Hadamard transform, N=4096 per row, fp32, scale 1/64. H4096 = H16^(x)3
// over hex digits e = c*256 + b*16 + a.
//
// R5: ONE WAVE PER ROW, ZERO BARRIERS.
//   R0-R4 all showed every pipe idle (VALU ~12%, HBM ~30%) regardless of
//   structure: inter-wave barriers on a ~2K-cycle work quantum phase-lock the
//   CU. Fix: wave owns the whole row in 16KB linear LDS (10 blocks/CU),
//   staged via 16x global_load_lds (zero VGPR -> regalloc can't sink it,
//   unlike R2/R3). Same-wave DS ordering + lgkmcnt(0) between passes is the
//   only sync. 10 autonomous waves/CU self-stagger -> continuous HBM demand.
//
// Bank-conflict design (linear LDS, bank = float_idx & 31), all passes <=2-way:
//   pass c: addr k*256 + (l + 64q)            -> bank l&31            : 2-way
//   pass b: XOR read/write order on b with rb = c&1 (two-base trick)  : 2-way
//   pass a: float4 chunks, read order XOR ra=(c+(m>>1))&3,
//           write pos XOR sw=(c+(tb>>1))&3                            : free
//   final : read pos XOR sk=(k+(l>>3))&3 == writer's sw               : free
// XOR input permutation of H16: out slot i = (-1)^{pop(i&R)} * y_i (exact),
// so permutes cost only per-lane-constant signs, folded into the final scale.

constexpr int N = 4096;

__device__ __forceinline__ void wht16(float v[16]) {
#pragma unroll
    for (int m = 1; m < 16; m <<= 1)
#pragma unroll
        for (int g = 0; g < 16; g += 2 * m)
#pragma unroll
            for (int k = 0; k < m; ++k) {
                float a = v[g + k], b = v[g + k + m];
                v[g + k]     = a + b;
                v[g + k + m] = a - b;
            }
}

__global__ __launch_bounds__(64) void fwht4096_kernel(const float* __restrict__ in,
                                                      float* __restrict__ out) {
    __shared__ __align__(16) float lds[N];   // 16384 B -> 10 blocks/CU

    const int l = threadIdx.x;               // lane 0..63
    const size_t row = blockIdx.x;
    const float* __restrict__ src = in + row * (size_t)N;
    float* __restrict__ dst = out + row * (size_t)N;

    // ---- stage row -> LDS, linear, zero VGPR. instr k: lane l loads 16B at
    // float idx k*256 + 4l; LDS dest wave-uniform base + lane*16 (linear). ----
    {
        const float* gp = src + l * 4;
#pragma unroll
        for (int k = 0; k < 16; ++k) {
            __builtin_amdgcn_global_load_lds(
                (const __attribute__((address_space(1))) unsigned int*)(gp + k * 256),
                (__attribute__((address_space(3))) unsigned int*)(lds + k * 256),
                16, 0, 0);
        }
    }
    asm volatile("s_waitcnt vmcnt(0)" ::: "memory");

    float v[16];
    const int rb = (l >> 4) & 1;   // = c&1 for this lane's groups (c = (l>>4)+4q)
    const int m  = l & 15;
    const int tb = m ^ rb;

    // ---- pass c: digit c. lane group g = l + 64q = (b,a); natural in-place. ----
#pragma unroll
    for (int q = 0; q < 4; ++q) {
        const int g = l + 64 * q;
#pragma unroll
        for (int k = 0; k < 16; ++k) v[k] = lds[k * 256 + g];
        wht16(v);
#pragma unroll
        for (int k = 0; k < 16; ++k) lds[k * 256 + g] = v[k];
    }
    asm volatile("s_waitcnt lgkmcnt(0)" ::: "memory");

    // ---- pass b: digit b for (c, a). slot j <-> location b = j^rb.
    // loc(c,mm,a) ends holding ((mm^rb)&rb ? -1:+1) * y2[c, mm^rb, a]. ----
#pragma unroll
    for (int q = 0; q < 4; ++q) {
        const int c  = (l >> 4) + 4 * q;
        const int e0 = c * 256 + m + 16 * rb;        // s=0: b = 2t + rb
        const int e1 = c * 256 + m + 16 * (1 - rb);  // s=1: b = 2t + (1^rb)
#pragma unroll
        for (int t = 0; t < 8; ++t) {
            v[2 * t]     = lds[e0 + 32 * t];
            v[2 * t + 1] = lds[e1 + 32 * t];
        }
        wht16(v);
#pragma unroll
        for (int t = 0; t < 8; ++t) {
            lds[e0 + 32 * t] = v[2 * t];
            lds[e1 + 32 * t] = v[2 * t + 1];
        }
    }
    asm volatile("s_waitcnt lgkmcnt(0)" ::: "memory");

    // ---- pass a: digit a for (c, m); true b = tb = m^rb (relabel).
    // read a-chunks in XOR-ra order; write chunks scrambled by sw; sign+scale
    // folded into per-chunk constants. ----
#pragma unroll
    for (int q = 0; q < 4; ++q) {
        const int c  = (l >> 4) + 4 * q;
        const int ra = (c + (m >> 1)) & 3;
        const int sw = (c + (tb >> 1)) & 3;
        const float4* lp4 = (const float4*)lds;
        const int rbase = c * 64 + m * 4;            // float4 units
        float4 ch0 = lp4[rbase + (0 ^ ra)];
        float4 ch1 = lp4[rbase + (1 ^ ra)];
        float4 ch2 = lp4[rbase + (2 ^ ra)];
        float4 ch3 = lp4[rbase + (3 ^ ra)];
        v[0]=ch0.x;  v[1]=ch0.y;  v[2]=ch0.z;  v[3]=ch0.w;
        v[4]=ch1.x;  v[5]=ch1.y;  v[6]=ch1.z;  v[7]=ch1.w;
        v[8]=ch2.x;  v[9]=ch2.y;  v[10]=ch2.z; v[11]=ch2.w;
        v[12]=ch3.x; v[13]=ch3.y; v[14]=ch3.z; v[15]=ch3.w;
        wht16(v);
        // sign: eps = (tb&rb ? -1:+1) from pass-b relabel; chunk w gets
        // (-1)^{pop(w & ra)} from the ra input-XOR. scale 1/64 folded in.
        const float bs  = (tb & rb) ? -0.015625f : 0.015625f;
        const float gs0 = bs;
        const float gs1 = (ra & 1) ? -bs : bs;
        const float gs2 = (ra & 2) ? -bs : bs;
        const float gs3 = (((ra & 1) ^ ((ra >> 1) & 1))) ? -bs : bs;
        float4* wp4 = (float4*)lds;
        const int wbase = c * 64 + tb * 4;           // float4 units
        wp4[wbase + (0 ^ sw)] = make_float4(v[0]*gs0,  v[1]*gs0,  v[2]*gs0,  v[3]*gs0);
        wp4[wbase + (1 ^ sw)] = make_float4(v[4]*gs1,  v[5]*gs1,  v[6]*gs1,  v[7]*gs1);
        wp4[wbase + (2 ^ sw)] = make_float4(v[8]*gs2,  v[9]*gs2,  v[10]*gs2, v[11]*gs2);
        wp4[wbase + (3 ^ sw)] = make_float4(v[12]*gs3, v[13]*gs3, v[14]*gs3, v[15]*gs3);
    }
    asm volatile("s_waitcnt lgkmcnt(0)" ::: "memory");

    // ---- final: linearize from scrambled LDS, fully-coalesced 1KB stores.
    // reader (c=k, tb=l>>2, chunk=l&3): pos = (l&3) ^ sk, sk=(k+(l>>3))&3 == sw. ----
    {
        const int l3  = l >> 3;
        const int lo  = l & 3;
        const int rb4 = (l >> 2) * 4;                // float4 units
        const int off0 = rb4 + (lo ^ ((0 + l3) & 3));
        const int off1 = rb4 + (lo ^ ((1 + l3) & 3));
        const int off2 = rb4 + (lo ^ ((2 + l3) & 3));
        const int off3 = rb4 + (lo ^ ((3 + l3) & 3));
        const float4* lp4 = (const float4*)lds;
#pragma unroll
        for (int k = 0; k < 16; ++k) {
            const int kk = k & 3;
            const int off = (kk == 0) ? off0 : (kk == 1) ? off1 : (kk == 2) ? off2 : off3;
            float4 val = lp4[k * 64 + off];
            *(float4*)(dst + k * 256 + 4 * l) = val;
        }
    }
}

extern "C" void kernel_launch(void* const* d_in, const int* in_sizes, int n_in,
                              void* d_out, int out_size, void* d_ws, size_t ws_size,
                              hipStream_t stream) {
    const float* x = (const float*)d_in[0];
    float* y = (float*)d_out;
    const int rows = in_sizes[0] / N;   // 8192
    fwht4096_kernel<<<rows, 64, 0, stream>>>(x, y);
}

// Round 6
// 228.462 us; speedup vs baseline: 1.0967x; 1.0056x over previous
//
#include <hip/hip_runtime.h>

// Walsh-Hadamard transform, N=4096 per row, fp32, scale 1/sqrt(4096)=1/64.
// H_4096 = H_16 (x) H_16 (x) H_16  -> three WHT16 passes over hex digits
// a=bits0-3, b=bits4-7, c=bits8-11, with two padded-LDS transposes between.
//
// R6 = R0 (best structure, ~72-75 us) + NON-TEMPORAL STORES. Single variable.
// Rationale: R0-R5 (barriers/none, 6-32 waves, VGPR/LDS-DMA staging, counted
// vmcnt pipelines) ALL hit ~2.5 TB/s with every pipe idle -> the wall is in
// the memory path, not kernel structure. Counter evidence: harness fill
// writes 537 MB @ 6.65 TB/s with FETCH~0 (streaming store path), while our
// FETCH is stably 65.6 MB = half the input: our cached output stores allocate
// in L3 (256 MB), evicting half the 128 MB input every iteration. NT stores
// stop output allocation -> input stays L3-resident, writes stream at fill
// rate. Predict FETCH < 25 MB, kernel 72 -> 45-60 us.

constexpr int N = 4096;
constexpr int LDS_STRIDE = 17;          // 16 + 1 pad: odd stride -> 2-way max (free)

__device__ __forceinline__ void wht16(float v[16]) {
#pragma unroll
    for (int m = 1; m < 16; m <<= 1) {
#pragma unroll
        for (int g = 0; g < 16; g += 2 * m) {
#pragma unroll
            for (int k = 0; k < m; ++k) {
                float a = v[g + k];
                float b = v[g + k + m];
                v[g + k]     = a + b;
                v[g + k + m] = a - b;
            }
        }
    }
}

__global__ __launch_bounds__(256, 4) void fwht4096_kernel(const float* __restrict__ in,
                                                          float* __restrict__ out) {
    // logical index within a row: e = c*256 + b*16 + a   (a,b,c in [0,16))
    // LDS physical map for a logical 256x16 tile: phys(i) = (i>>4)*17 + (i&15)
    __shared__ float lds[256 * LDS_STRIDE];

    const int t = threadIdx.x;
    const size_t row = blockIdx.x;
    const float* __restrict__ src = in + row * (size_t)N;
    float* __restrict__ dst = out + row * (size_t)N;

    float v[16];

    // ---- phase 1: thread t holds e = t*16 + j  (c=t>>4, b=t&15, a=j) ----
    {
        const float4* s4 = (const float4*)(src + t * 16);
        float4 f0 = s4[0], f1 = s4[1], f2 = s4[2], f3 = s4[3];
        v[0]=f0.x;  v[1]=f0.y;  v[2]=f0.z;  v[3]=f0.w;
        v[4]=f1.x;  v[5]=f1.y;  v[6]=f1.z;  v[7]=f1.w;
        v[8]=f2.x;  v[9]=f2.y;  v[10]=f2.z; v[11]=f2.w;
        v[12]=f3.x; v[13]=f3.y; v[14]=f3.z; v[15]=f3.w;
    }
    wht16(v);   // digit a done

    // ---- transpose 1: logical layout i = c*256 + a*16 + b ----
    // writer: i = (t>>4)*256 + j*16 + (t&15)  -> phys = ((t>>4)*16 + j)*17 + (t&15)
    {
        const int base = (t >> 4) * (16 * LDS_STRIDE) + (t & 15);
#pragma unroll
        for (int j = 0; j < 16; ++j) lds[base + j * LDS_STRIDE] = v[j];
    }
    __syncthreads();
    // reader: i = t*16 + p  (c=t>>4, a=t&15, b=p) -> phys = t*17 + p  (contiguous)
    {
        const int base = t * LDS_STRIDE;
#pragma unroll
        for (int p = 0; p < 16; ++p) v[p] = lds[base + p];
    }
    wht16(v);   // digit b done
    __syncthreads();   // protect LDS before overwrite

    // ---- transpose 2: logical layout i = b*256 + a*16 + c ----
    // writer: i = j*256 + (t&15)*16 + (t>>4) -> phys = (j*16 + (t&15))*17 + (t>>4)
    {
        const int base = (t & 15) * LDS_STRIDE + (t >> 4);
#pragma unroll
        for (int j = 0; j < 16; ++j) lds[base + j * (16 * LDS_STRIDE)] = v[j];
    }
    __syncthreads();
    // reader: i = t*16 + p  (b=t>>4, a=t&15, c=p) -> phys = t*17 + p
    {
        const int base = t * LDS_STRIDE;
#pragma unroll
        for (int p = 0; p < 16; ++p) v[p] = lds[base + p];
    }
    wht16(v);   // digit c done

    // ---- store: element e = p*256 + (t>>4)*16 + (t&15) = p*256 + t ----
    // NON-TEMPORAL: output is write-once; bypass L2/L3 allocation so the
    // input stays LLC-resident across bench iterations (see header).
    // Per-wave each instr still covers 256 B contiguous (full 64B lines).
    const float scale = 0.015625f;  // 1/64 = 1/sqrt(4096)
#pragma unroll
    for (int p = 0; p < 16; ++p)
        __builtin_nontemporal_store(v[p] * scale, &dst[p * 256 + t]);
}

extern "C" void kernel_launch(void* const* d_in, const int* in_sizes, int n_in,
                              void* d_out, int out_size, void* d_ws, size_t ws_size,
                              hipStream_t stream) {
    const float* x = (const float*)d_in[0];
    float* y = (float*)d_out;
    const int rows = in_sizes[0] / N;   // 4*2048 = 8192
    fwht4096_kernel<<<rows, 256, 0, stream>>>(x, y);
}